// Round 15
// baseline (148.841 us; speedup 1.0000x reference)
//
#include <hip/hip_runtime.h>
#include <hip/hip_bf16.h>

// CausalAttention MI355X: B=2 L=2048 D=1024 H=16 HD=64
// convert -> QKV GEMM (256x128 tile, K-ring stagger, XCD swizzle) ->
// transpose_v -> flash attention (KVBLK=128, dual-stream online softmax,
// XCD-local, sum-15 pairing, base-2 + defer-max) -> out GEMM (128^2).

using bf16x8 = __attribute__((ext_vector_type(8))) short;
using f32x4  = __attribute__((ext_vector_type(4))) float;

static __device__ __forceinline__ unsigned short f2b(float f) {
  unsigned u = __builtin_bit_cast(unsigned, f);
  unsigned r = (u + 0x7fffu + ((u >> 16) & 1u)) >> 16;
  return (unsigned short)r;
}

// pack 2 f32 -> 2 bf16 in one instr (no builtin on gfx950; T12 recipe)
static __device__ __forceinline__ unsigned cvtpk(float lo, float hi) {
  unsigned r;
  asm("v_cvt_pk_bf16_f32 %0, %1, %2" : "=v"(r) : "v"(lo), "v"(hi));
  return r;
}

// async global->LDS, 16B/lane; LDS dest wave-uniform (HW adds lane*16),
// per-lane row/swizzle on the GLOBAL address (rule 21 / m173).
static __device__ __forceinline__ void gl_lds16(const void* g, void* l) {
  __builtin_amdgcn_global_load_lds(
      (const __attribute__((address_space(1))) unsigned int*)g,
      (__attribute__((address_space(3))) unsigned int*)l, 16, 0, 0);
}

// ---------------------------------------------------------------- converts
__global__ __launch_bounds__(256) void convert_bf16(
    const float* __restrict__ in, unsigned short* __restrict__ out, int n8) {
  int i = blockIdx.x * 256 + threadIdx.x;
  if (i >= n8) return;
  const float4* p = reinterpret_cast<const float4*>(in) + (size_t)i * 2;
  float4 a = p[0], b = p[1];
  bf16x8 o;
  o[0] = f2b(a.x); o[1] = f2b(a.y); o[2] = f2b(a.z); o[3] = f2b(a.w);
  o[4] = f2b(b.x); o[5] = f2b(b.y); o[6] = f2b(b.z); o[7] = f2b(b.w);
  reinterpret_cast<bf16x8*>(out)[i] = o;
}

__global__ __launch_bounds__(256) void transpose_convert(
    const float* __restrict__ w, unsigned short* __restrict__ wt, int K, int N) {
  int idx = blockIdx.x * 256 + threadIdx.x;
  int n  = idx % N;
  int k0 = (idx / N) * 8;
  if (k0 >= K) return;
  bf16x8 o;
#pragma unroll
  for (int j = 0; j < 8; ++j) o[j] = f2b(w[(size_t)(k0 + j) * N + n]);
  *reinterpret_cast<bf16x8*>(&wt[(size_t)n * K + k0]) = o;
}

// V [bh][l][64] -> V^T [bh][64][2048] via LDS tile
__global__ __launch_bounds__(256) void transpose_v(
    const unsigned short* __restrict__ vb, unsigned short* __restrict__ vt) {
  __shared__ unsigned short T[64][72];
  const int bh = blockIdx.y, l0 = blockIdx.x * 64;
  const int row = threadIdx.x >> 2;
  const int qc  = threadIdx.x & 3;
#pragma unroll
  for (int h = 0; h < 2; ++h) {
    bf16x8 v = *reinterpret_cast<const bf16x8*>(
        &vb[((size_t)bh * 2048 + l0 + row) * 64 + h * 32 + qc * 8]);
#pragma unroll
    for (int j = 0; j < 8; ++j) T[h * 32 + qc * 8 + j][row] = (unsigned short)v[j];
  }
  __syncthreads();
#pragma unroll
  for (int h = 0; h < 2; ++h) {
    bf16x8 o = *reinterpret_cast<const bf16x8*>(&T[row][h * 32 + qc * 8]);
    *reinterpret_cast<bf16x8*>(
        &vt[((size_t)bh * 64 + row) * 2048 + l0 + h * 32 + qc * 8]) = o;
  }
}

// ------------------------------------------------ QKV GEMM: 256x128, stagger
// (R10 verified; q scaled by 0.125*log2e for base-2 softmax downstream)
__global__ __launch_bounds__(512) void gemm_qkv(
    const unsigned short* __restrict__ A,
    const unsigned short* __restrict__ Bt,
    const float* __restrict__ bias,
    unsigned short* __restrict__ qb, unsigned short* __restrict__ kb,
    unsigned short* __restrict__ vb) {
  __shared__ __align__(16) unsigned short lA[256 * 64];
  __shared__ __align__(16) unsigned short lB[128 * 64];
  const int t = threadIdx.x;
  const int lin = blockIdx.y * 24 + blockIdx.x;          // grid (24,16)
  const int nb  = (lin & 7) * 48 + (lin >> 3);
  const int bm = nb / 24, bn = nb % 24;
  const int s0 = (nb * 5) & 15;
  const int w = t >> 6, lane = t & 63;
  const int lr = lane & 15, lg = lane >> 4;
  const int wm = (w >> 1) * 64, wn = (w & 1) * 64;
  const int g8  = lane >> 3;
  const int swz = ((lane & 7) * 16) ^ (g8 << 4);

  f32x4 acc[4][4];
#pragma unroll
  for (int i = 0; i < 4; ++i)
#pragma unroll
    for (int j = 0; j < 4; ++j) acc[i][j] = f32x4{0.f, 0.f, 0.f, 0.f};

  const size_t am = (size_t)bm * 256, bnr = (size_t)bn * 128;

  for (int kt = 0; kt < 16; ++kt) {
    const int k0 = ((kt + s0) & 15) * 64;
#pragma unroll
    for (int i = 0; i < 4; ++i) {                 // A: 256 rows
      const int rs = i * 64 + w * 8;
      gl_lds16((const char*)(A + (am + rs + g8) * 1024 + k0) + swz,
               (char*)lA + rs * 128);
    }
#pragma unroll
    for (int i = 0; i < 2; ++i) {                 // B: 128 rows
      const int rs = i * 64 + w * 8;
      gl_lds16((const char*)(Bt + (bnr + rs + g8) * 1024 + k0) + swz,
               (char*)lB + rs * 128);
    }
    __syncthreads();
#pragma unroll
    for (int kk = 0; kk < 64; kk += 32) {
      bf16x8 af[4], bfr[4];
#pragma unroll
      for (int fm = 0; fm < 4; ++fm) {
        int row = wm + fm * 16 + lr;
        af[fm] = *reinterpret_cast<const bf16x8*>(
            (const char*)lA + row * 128 + ((2 * kk + lg * 16) ^ ((lr & 7) << 4)));
      }
#pragma unroll
      for (int fn = 0; fn < 4; ++fn) {
        int row = wn + fn * 16 + lr;
        bfr[fn] = *reinterpret_cast<const bf16x8*>(
            (const char*)lB + row * 128 + ((2 * kk + lg * 16) ^ ((lr & 7) << 4)));
      }
#pragma unroll
      for (int fm = 0; fm < 4; ++fm)
#pragma unroll
        for (int fn = 0; fn < 4; ++fn)
          acc[fm][fn] = __builtin_amdgcn_mfma_f32_16x16x32_bf16(
              af[fm], bfr[fn], acc[fm][fn], 0, 0, 0);
    }
    __syncthreads();
  }

#pragma unroll
  for (int fm = 0; fm < 4; ++fm) {
#pragma unroll
    for (int fn = 0; fn < 4; ++fn) {
#pragma unroll
      for (int r = 0; r < 4; ++r) {
        int row = bm * 256 + wm + fm * 16 + lg * 4 + r;
        int col = bn * 128 + wn + fn * 16 + lr;
        float v = acc[fm][fn][r] + bias[col];
        int bb = row >> 11, l = row & 2047;
        int which = col >> 10, hn = col & 1023;
        int h = hn >> 6, d = hn & 63;
        int bh = bb * 16 + h;
        if (which == 0)
          qb[((size_t)bh * 2048 + l) * 64 + d] = f2b(v * 0.180336879f); // 0.125*log2e
        else if (which == 1)
          kb[((size_t)bh * 2048 + l) * 64 + d] = f2b(v);
        else
          vb[((size_t)bh * 2048 + l) * 64 + d] = f2b(v);
      }
    }
  }
}

// ---------------------------------------------------------------- out GEMM
// (R10 verified)
__global__ __launch_bounds__(256) void gemm128(
    const unsigned short* __restrict__ A,
    const unsigned short* __restrict__ Bt,
    const float* __restrict__ bias, float* __restrict__ outf) {
  __shared__ __align__(16) unsigned short lA[128 * 64];
  __shared__ __align__(16) unsigned short lB[128 * 64];
  const int t = threadIdx.x;
  const int lin = blockIdx.y * 8 + blockIdx.x;          // grid (8,32)
  const int nb  = (lin & 7) * 32 + (lin >> 3);
  const int bm = nb >> 3, bn = nb & 7;
  const int s0 = (nb * 5) & 15;
  const int w = t >> 6, lane = t & 63;
  const int lr = lane & 15, lg = lane >> 4;
  const int wm = (w >> 1) * 64, wn = (w & 1) * 64;
  const int g8  = lane >> 3;
  const int swz = ((lane & 7) * 16) ^ (g8 << 4);

  f32x4 acc[4][4];
#pragma unroll
  for (int i = 0; i < 4; ++i)
#pragma unroll
    for (int j = 0; j < 4; ++j) acc[i][j] = f32x4{0.f, 0.f, 0.f, 0.f};

  const size_t am = (size_t)bm * 128, bnr = (size_t)bn * 128;

  for (int kt = 0; kt < 16; ++kt) {
    const int k0 = ((kt + s0) & 15) * 64;
#pragma unroll
    for (int i = 0; i < 4; ++i) {
      const int rs = i * 32 + w * 8;
      gl_lds16((const char*)(A + (am + rs + g8) * 1024 + k0) + swz,
               (char*)lA + rs * 128);
      gl_lds16((const char*)(Bt + (bnr + rs + g8) * 1024 + k0) + swz,
               (char*)lB + rs * 128);
    }
    __syncthreads();
#pragma unroll
    for (int kk = 0; kk < 64; kk += 32) {
      bf16x8 af[4], bfr[4];
#pragma unroll
      for (int fm = 0; fm < 4; ++fm) {
        int row = wm + fm * 16 + lr;
        af[fm] = *reinterpret_cast<const bf16x8*>(
            (const char*)lA + row * 128 + ((2 * kk + lg * 16) ^ ((lr & 7) << 4)));
      }
#pragma unroll
      for (int fn = 0; fn < 4; ++fn) {
        int row = wn + fn * 16 + lr;
        bfr[fn] = *reinterpret_cast<const bf16x8*>(
            (const char*)lB + row * 128 + ((2 * kk + lg * 16) ^ ((lr & 7) << 4)));
      }
#pragma unroll
      for (int fm = 0; fm < 4; ++fm)
#pragma unroll
        for (int fn = 0; fn < 4; ++fn)
          acc[fm][fn] = __builtin_amdgcn_mfma_f32_16x16x32_bf16(
              af[fm], bfr[fn], acc[fm][fn], 0, 0, 0);
    }
    __syncthreads();
  }

#pragma unroll
  for (int fm = 0; fm < 4; ++fm)
#pragma unroll
    for (int fn = 0; fn < 4; ++fn)
#pragma unroll
      for (int r = 0; r < 4; ++r) {
        int row = bm * 128 + wm + fm * 16 + lg * 4 + r;
        int col = bn * 128 + wn + fn * 16 + lr;
        outf[(size_t)row * 1024 + col] = acc[fm][fn][r] + bias[col];
      }
}

// ---------------------------------------------------------------- attention
// R13 structure (KVBLK=128, 16x16 frags, pl swizzled) + DUAL-STREAM online
// softmax: state A owns even chunks (buf0), state B odd chunks (buf1) --
// independent dependency chains, merged in the epilogue. All state indexing
// static (rule #20): loop unrolled x2 with named stateA/stateB.
__global__ __launch_bounds__(256, 2) void attn_kernel(
    const unsigned short* __restrict__ qb, const unsigned short* __restrict__ kb,
    const unsigned short* __restrict__ vt, unsigned short* __restrict__ attnb) {
  __shared__ __align__(16) unsigned short lK[2][128 * 64];
  __shared__ __align__(16) unsigned short lV[2][2][64 * 64];
  __shared__ __align__(16) unsigned short pl[4][16 * 128];
  const int bid = blockIdx.x;
  const int xcd = bid & 7, pos = bid >> 3;
  const int half = pos >> 5, idx = pos & 31;
  const int bh = xcd * 4 + half * 2 + (idx >> 4);
  const int qt = half ? (15 - (idx & 15)) : (idx & 15);
  const int q0 = qt * 128;
  const int w = threadIdx.x >> 6, lane = threadIdx.x & 63;
  const int lr = lane & 15, lg = lane >> 4;
  const int g8  = lane >> 3;
  const int swz = ((lane & 7) * 16) ^ (g8 << 4);

  const unsigned short* Kg = kb + (size_t)bh * 2048 * 64;
  const unsigned short* Vg = vt + (size_t)bh * 64 * 2048;

  auto stage = [&](int buf, int c) {
    const size_t kv0 = (size_t)c * 128;
#pragma unroll
    for (int i = 0; i < 4; ++i) {
      const int rs = i * 32 + w * 8;
      gl_lds16((const char*)(Kg + (kv0 + rs + g8) * 64) + swz,
               (char*)&lK[buf][0] + rs * 128);
    }
#pragma unroll
    for (int h = 0; h < 2; ++h)
#pragma unroll
      for (int i = 0; i < 2; ++i) {
        const int rs = i * 32 + w * 8;
        gl_lds16((const char*)(Vg + (size_t)(rs + g8) * 2048 + kv0 + h * 64) + swz,
                 (char*)&lV[buf][h][0] + rs * 128);
      }
  };

  bf16x8 qf[2][2];
#pragma unroll
  for (int qi = 0; qi < 2; ++qi)
#pragma unroll
    for (int kk = 0; kk < 2; ++kk)
      qf[qi][kk] = *reinterpret_cast<const bf16x8*>(
          &qb[((size_t)bh * 2048 + q0 + w * 32 + qi * 16 + lr) * 64 + kk * 32 + lg * 8]);

  f32x4 accA[2][4], accB[2][4];
#pragma unroll
  for (int qi = 0; qi < 2; ++qi)
#pragma unroll
    for (int i = 0; i < 4; ++i) {
      accA[qi][i] = f32x4{0.f, 0.f, 0.f, 0.f};
      accB[qi][i] = f32x4{0.f, 0.f, 0.f, 0.f};
    }
  float mA[2] = {-1e30f, -1e30f}, rsA[2] = {0.f, 0.f};
  float mB[2] = {-1e30f, -1e30f}, rsB[2] = {0.f, 0.f};

  // one chunk: QK (buf) -> softmax into (m,rs) -> PV into acc
  auto process = [&](int c, int buf, float (&m)[2], float (&rs)[2],
                     f32x4 (&acc)[2][4]) {
    f32x4 s[2][8];
#pragma unroll
    for (int qi = 0; qi < 2; ++qi)
#pragma unroll
      for (int i = 0; i < 8; ++i) s[qi][i] = f32x4{0.f, 0.f, 0.f, 0.f};
#pragma unroll
    for (int nf = 0; nf < 8; ++nf) {
      const int row = nf * 16 + lr;
      bf16x8 k0 = *reinterpret_cast<const bf16x8*>(
          (const char*)&lK[buf][0] + row * 128 + ((lg * 16) ^ ((lr & 7) << 4)));
      bf16x8 k1 = *reinterpret_cast<const bf16x8*>(
          (const char*)&lK[buf][0] + row * 128 + ((64 + lg * 16) ^ ((lr & 7) << 4)));
#pragma unroll
      for (int qi = 0; qi < 2; ++qi) {
        s[qi][nf] = __builtin_amdgcn_mfma_f32_16x16x32_bf16(k0, qf[qi][0], s[qi][nf], 0, 0, 0);
        s[qi][nf] = __builtin_amdgcn_mfma_f32_16x16x32_bf16(k1, qf[qi][1], s[qi][nf], 0, 0, 0);
      }
    }

#pragma unroll
    for (int qi = 0; qi < 2; ++qi) {
      const int qrow = q0 + w * 32 + qi * 16 + lr;
      const bool diag = (c * 128 + 127) > (q0 + w * 32 + qi * 16);
      float ps[8][4];
      float mx = -1e30f;
      if (diag) {
#pragma unroll
        for (int nf = 0; nf < 8; ++nf)
#pragma unroll
          for (int r = 0; r < 4; ++r) {
            int key = c * 128 + nf * 16 + lg * 4 + r;
            float sv = (key <= qrow) ? s[qi][nf][r] : -1e30f;
            ps[nf][r] = sv;
            mx = fmaxf(mx, sv);
          }
      } else {
#pragma unroll
        for (int nf = 0; nf < 8; ++nf)
#pragma unroll
          for (int r = 0; r < 4; ++r) {
            ps[nf][r] = s[qi][nf][r];
            mx = fmaxf(mx, ps[nf][r]);
          }
      }
      mx = fmaxf(mx, __shfl_xor(mx, 16));
      mx = fmaxf(mx, __shfl_xor(mx, 32));
      if (__any(mx > m[qi] + 8.f)) {            // defer-max (T13)
        float mn = fmaxf(m[qi], mx);
        float scl = exp2f(m[qi] - mn);
        m[qi] = mn;
        rs[qi] *= scl;
#pragma unroll
        for (int df = 0; df < 4; ++df) acc[qi][df] *= scl;
      }
      float ss = 0.f;
#pragma unroll
      for (int nf = 0; nf < 8; ++nf)
#pragma unroll
        for (int r = 0; r < 4; ++r) {
          float pe = exp2f(ps[nf][r] - m[qi]);
          ps[nf][r] = pe;
          ss += pe;
        }
      ss += __shfl_xor(ss, 16);
      ss += __shfl_xor(ss, 32);
      rs[qi] += ss;

#pragma unroll
      for (int nf = 0; nf < 8; ++nf) {
        uint2 pk;
        pk.x = cvtpk(ps[nf][0], ps[nf][1]);
        pk.y = cvtpk(ps[nf][2], ps[nf][3]);
        *reinterpret_cast<uint2*>(
            (char*)&pl[w][0] + lr * 256 + ((nf * 32 + lg * 8) ^ ((lr & 7) << 4))) = pk;
      }
#pragma unroll
      for (int kk = 0; kk < 4; ++kk) {
        bf16x8 pf = *reinterpret_cast<const bf16x8*>(
            (const char*)&pl[w][0] + lr * 256 + ((kk * 64 + lg * 16) ^ ((lr & 7) << 4)));
#pragma unroll
        for (int df = 0; df < 4; ++df) {
          const int row = df * 16 + lr;
          bf16x8 vf = *reinterpret_cast<const bf16x8*>(
              (const char*)&lV[buf][kk >> 1][0] + row * 128 +
              (((kk & 1) * 64 + lg * 16) ^ ((lr & 7) << 4)));
          acc[qi][df] = __builtin_amdgcn_mfma_f32_16x16x32_bf16(vf, pf, acc[qi][df], 0, 0, 0);
        }
      }
    }
  };

  const int nc = qt + 1;   // chunks of 128 keys
  stage(0, 0);

  for (int c = 0; c < nc; c += 2) {
    __syncthreads();                        // buf0 ready; prior readers done
    if (c + 1 < nc) stage(1, c + 1);
    process(c, 0, mA, rsA, accA);
    if (c + 1 < nc) {
      __syncthreads();                      // buf1 ready; buf0 readers done
      if (c + 2 < nc) stage(0, c + 2);
      process(c + 1, 1, mB, rsB, accB);
    }
  }

  // merge dual streams + write O
  const int b = bh >> 4, h = bh & 15;
#pragma unroll
  for (int qi = 0; qi < 2; ++qi) {
    float mm = fmaxf(mA[qi], mB[qi]);
    float sA = exp2f(mA[qi] - mm), sB = exp2f(mB[qi] - mm);
    float inv = 1.f / (rsA[qi] * sA + rsB[qi] * sB);
    int qrow = q0 + w * 32 + qi * 16 + lr;
#pragma unroll
    for (int df = 0; df < 4; ++df) {
      ushort4 ov;
      ov.x = f2b((accA[qi][df][0] * sA + accB[qi][df][0] * sB) * inv);
      ov.y = f2b((accA[qi][df][1] * sA + accB[qi][df][1] * sB) * inv);
      ov.z = f2b((accA[qi][df][2] * sA + accB[qi][df][2] * sB) * inv);
      ov.w = f2b((accA[qi][df][3] * sA + accB[qi][df][3] * sB) * inv);
      *reinterpret_cast<ushort4*>(
          &attnb[((size_t)b * 2048 + qrow) * 1024 + h * 64 + df * 16 + lg * 4]) = ov;
    }
  }
}

// ---------------------------------------------------------------- launch
extern "C" void kernel_launch(void* const* d_in, const int* in_sizes, int n_in,
                              void* d_out, int out_size, void* d_ws, size_t ws_size,
                              hipStream_t stream) {
  const float* x     = (const float*)d_in[0];
  const float* w_qkv = (const float*)d_in[1];
  const float* b_qkv = (const float*)d_in[2];
  const float* w_out = (const float*)d_in[3];
  const float* b_out = (const float*)d_in[4];
  float* out = (float*)d_out;
  char* ws = (char*)d_ws;

  unsigned short* xb    = (unsigned short*)(ws);               //  8.0 MB (-> vt)
  unsigned short* vt    = (unsigned short*)(ws);
  unsigned short* wqkvt = (unsigned short*)(ws + 8388608);     //  6.0 MB
  unsigned short* woutt = (unsigned short*)(ws + 14680064);    //  2.0 MB
  unsigned short* qb    = (unsigned short*)(ws + 16777216);    //  8.0 MB
  unsigned short* kb    = (unsigned short*)(ws + 25165824);    //  8.0 MB
  unsigned short* vb    = (unsigned short*)(ws + 33554432);    //  8.0 MB
  unsigned short* attnb = (unsigned short*)(ws + 41943040);    //  8.0 MB

  convert_bf16<<<2048, 256, 0, stream>>>(x, xb, 4194304 / 8);
  transpose_convert<<<1536, 256, 0, stream>>>(w_qkv, wqkvt, 1024, 3072);
  transpose_convert<<<512, 256, 0, stream>>>(w_out, woutt, 1024, 1024);
  gemm_qkv<<<dim3(24, 16), 512, 0, stream>>>(xb, wqkvt, b_qkv, qb, kb, vb);
  transpose_v<<<dim3(32, 32), 256, 0, stream>>>(vb, vt);
  attn_kernel<<<512, 256, 0, stream>>>(qb, kb, vt, attnb);
  gemm128<<<dim3(8, 32), 256, 0, stream>>>(attnb, woutt, b_out, out);
}

// Round 16
// 130.880 us; speedup vs baseline: 1.1372x; 1.1372x over previous
//
#include <hip/hip_runtime.h>
#include <hip/hip_bf16.h>

// CausalAttention MI355X: B=2 L=2048 D=1024 H=16 HD=64
// convert -> QKV GEMM (256x128 tile, K-ring stagger, XCD swizzle) ->
// transpose_v -> flash attention (R13 verified: KVBLK=128, XCD-local,
// sum-15 pairing, base-2 + defer-max) -> out GEMM (128x64, 2/CU stagger).

using bf16x8 = __attribute__((ext_vector_type(8))) short;
using f32x4  = __attribute__((ext_vector_type(4))) float;

static __device__ __forceinline__ unsigned short f2b(float f) {
  unsigned u = __builtin_bit_cast(unsigned, f);
  unsigned r = (u + 0x7fffu + ((u >> 16) & 1u)) >> 16;
  return (unsigned short)r;
}

// pack 2 f32 -> 2 bf16 in one instr (no builtin on gfx950; T12 recipe)
static __device__ __forceinline__ unsigned cvtpk(float lo, float hi) {
  unsigned r;
  asm("v_cvt_pk_bf16_f32 %0, %1, %2" : "=v"(r) : "v"(lo), "v"(hi));
  return r;
}

// async global->LDS, 16B/lane; LDS dest wave-uniform (HW adds lane*16),
// per-lane row/swizzle on the GLOBAL address (rule 21 / m173).
static __device__ __forceinline__ void gl_lds16(const void* g, void* l) {
  __builtin_amdgcn_global_load_lds(
      (const __attribute__((address_space(1))) unsigned int*)g,
      (__attribute__((address_space(3))) unsigned int*)l, 16, 0, 0);
}

// ---------------------------------------------------------------- converts
__global__ __launch_bounds__(256) void convert_bf16(
    const float* __restrict__ in, unsigned short* __restrict__ out, int n8) {
  int i = blockIdx.x * 256 + threadIdx.x;
  if (i >= n8) return;
  const float4* p = reinterpret_cast<const float4*>(in) + (size_t)i * 2;
  float4 a = p[0], b = p[1];
  bf16x8 o;
  o[0] = f2b(a.x); o[1] = f2b(a.y); o[2] = f2b(a.z); o[3] = f2b(a.w);
  o[4] = f2b(b.x); o[5] = f2b(b.y); o[6] = f2b(b.z); o[7] = f2b(b.w);
  reinterpret_cast<bf16x8*>(out)[i] = o;
}

__global__ __launch_bounds__(256) void transpose_convert(
    const float* __restrict__ w, unsigned short* __restrict__ wt, int K, int N) {
  int idx = blockIdx.x * 256 + threadIdx.x;
  int n  = idx % N;
  int k0 = (idx / N) * 8;
  if (k0 >= K) return;
  bf16x8 o;
#pragma unroll
  for (int j = 0; j < 8; ++j) o[j] = f2b(w[(size_t)(k0 + j) * N + n]);
  *reinterpret_cast<bf16x8*>(&wt[(size_t)n * K + k0]) = o;
}

// V [bh][l][64] -> V^T [bh][64][2048] via LDS tile
__global__ __launch_bounds__(256) void transpose_v(
    const unsigned short* __restrict__ vb, unsigned short* __restrict__ vt) {
  __shared__ unsigned short T[64][72];
  const int bh = blockIdx.y, l0 = blockIdx.x * 64;
  const int row = threadIdx.x >> 2;
  const int qc  = threadIdx.x & 3;
#pragma unroll
  for (int h = 0; h < 2; ++h) {
    bf16x8 v = *reinterpret_cast<const bf16x8*>(
        &vb[((size_t)bh * 2048 + l0 + row) * 64 + h * 32 + qc * 8]);
#pragma unroll
    for (int j = 0; j < 8; ++j) T[h * 32 + qc * 8 + j][row] = (unsigned short)v[j];
  }
  __syncthreads();
#pragma unroll
  for (int h = 0; h < 2; ++h) {
    bf16x8 o = *reinterpret_cast<const bf16x8*>(&T[row][h * 32 + qc * 8]);
    *reinterpret_cast<bf16x8*>(
        &vt[((size_t)bh * 64 + row) * 2048 + l0 + h * 32 + qc * 8]) = o;
  }
}

// ------------------------------------------------ QKV GEMM: 256x128, stagger
// (R10 verified; q scaled by 0.125*log2e for base-2 softmax downstream)
__global__ __launch_bounds__(512) void gemm_qkv(
    const unsigned short* __restrict__ A,
    const unsigned short* __restrict__ Bt,
    const float* __restrict__ bias,
    unsigned short* __restrict__ qb, unsigned short* __restrict__ kb,
    unsigned short* __restrict__ vb) {
  __shared__ __align__(16) unsigned short lA[256 * 64];
  __shared__ __align__(16) unsigned short lB[128 * 64];
  const int t = threadIdx.x;
  const int lin = blockIdx.y * 24 + blockIdx.x;          // grid (24,16)
  const int nb  = (lin & 7) * 48 + (lin >> 3);
  const int bm = nb / 24, bn = nb % 24;
  const int s0 = (nb * 5) & 15;
  const int w = t >> 6, lane = t & 63;
  const int lr = lane & 15, lg = lane >> 4;
  const int wm = (w >> 1) * 64, wn = (w & 1) * 64;
  const int g8  = lane >> 3;
  const int swz = ((lane & 7) * 16) ^ (g8 << 4);

  f32x4 acc[4][4];
#pragma unroll
  for (int i = 0; i < 4; ++i)
#pragma unroll
    for (int j = 0; j < 4; ++j) acc[i][j] = f32x4{0.f, 0.f, 0.f, 0.f};

  const size_t am = (size_t)bm * 256, bnr = (size_t)bn * 128;

  for (int kt = 0; kt < 16; ++kt) {
    const int k0 = ((kt + s0) & 15) * 64;
#pragma unroll
    for (int i = 0; i < 4; ++i) {                 // A: 256 rows
      const int rs = i * 64 + w * 8;
      gl_lds16((const char*)(A + (am + rs + g8) * 1024 + k0) + swz,
               (char*)lA + rs * 128);
    }
#pragma unroll
    for (int i = 0; i < 2; ++i) {                 // B: 128 rows
      const int rs = i * 64 + w * 8;
      gl_lds16((const char*)(Bt + (bnr + rs + g8) * 1024 + k0) + swz,
               (char*)lB + rs * 128);
    }
    __syncthreads();
#pragma unroll
    for (int kk = 0; kk < 64; kk += 32) {
      bf16x8 af[4], bfr[4];
#pragma unroll
      for (int fm = 0; fm < 4; ++fm) {
        int row = wm + fm * 16 + lr;
        af[fm] = *reinterpret_cast<const bf16x8*>(
            (const char*)lA + row * 128 + ((2 * kk + lg * 16) ^ ((lr & 7) << 4)));
      }
#pragma unroll
      for (int fn = 0; fn < 4; ++fn) {
        int row = wn + fn * 16 + lr;
        bfr[fn] = *reinterpret_cast<const bf16x8*>(
            (const char*)lB + row * 128 + ((2 * kk + lg * 16) ^ ((lr & 7) << 4)));
      }
#pragma unroll
      for (int fm = 0; fm < 4; ++fm)
#pragma unroll
        for (int fn = 0; fn < 4; ++fn)
          acc[fm][fn] = __builtin_amdgcn_mfma_f32_16x16x32_bf16(
              af[fm], bfr[fn], acc[fm][fn], 0, 0, 0);
    }
    __syncthreads();
  }

#pragma unroll
  for (int fm = 0; fm < 4; ++fm) {
#pragma unroll
    for (int fn = 0; fn < 4; ++fn) {
#pragma unroll
      for (int r = 0; r < 4; ++r) {
        int row = bm * 256 + wm + fm * 16 + lg * 4 + r;
        int col = bn * 128 + wn + fn * 16 + lr;
        float v = acc[fm][fn][r] + bias[col];
        int bb = row >> 11, l = row & 2047;
        int which = col >> 10, hn = col & 1023;
        int h = hn >> 6, d = hn & 63;
        int bh = bb * 16 + h;
        if (which == 0)
          qb[((size_t)bh * 2048 + l) * 64 + d] = f2b(v * 0.180336879f); // 0.125*log2e
        else if (which == 1)
          kb[((size_t)bh * 2048 + l) * 64 + d] = f2b(v);
        else
          vb[((size_t)bh * 2048 + l) * 64 + d] = f2b(v);
      }
    }
  }
}

// ---------------------------------------------------------------- out GEMM
// 128x64 tile -> grid 512 = 2 blocks/CU so K-ring stagger has a partner
// to de-phase against (1-block/CU grids can't overlap stage & compute
// across blocks -- the R4-R9 ~1.2 TF/CU wall). Wave tile 64x32 (acc[4][2]).
__global__ __launch_bounds__(256) void gemm_out(
    const unsigned short* __restrict__ A,
    const unsigned short* __restrict__ Bt,
    const float* __restrict__ bias, float* __restrict__ outf) {
  __shared__ __align__(16) unsigned short lA[128 * 64];
  __shared__ __align__(16) unsigned short lB[64 * 64];
  const int t = threadIdx.x;
  const int lin = blockIdx.y * 16 + blockIdx.x;         // grid (16,32)
  const int nb  = (lin & 7) * 64 + (lin >> 3);          // bijective, 64/XCD
  const int bm = nb >> 4, bn = nb & 15;
  const int s0 = (nb * 5) & 15;
  const int w = t >> 6, lane = t & 63;
  const int lr = lane & 15, lg = lane >> 4;
  const int wm = (w >> 1) * 64, wn = (w & 1) * 32;
  const int g8  = lane >> 3;
  const int swz = ((lane & 7) * 16) ^ (g8 << 4);

  f32x4 acc[4][2];
#pragma unroll
  for (int i = 0; i < 4; ++i)
#pragma unroll
    for (int j = 0; j < 2; ++j) acc[i][j] = f32x4{0.f, 0.f, 0.f, 0.f};

  const size_t am = (size_t)bm * 128, bnr = (size_t)bn * 64;

  for (int kt = 0; kt < 16; ++kt) {
    const int k0 = ((kt + s0) & 15) * 64;
#pragma unroll
    for (int i = 0; i < 4; ++i) {                 // A: 128 rows
      const int rs = i * 32 + w * 8;
      gl_lds16((const char*)(A + (am + rs + g8) * 1024 + k0) + swz,
               (char*)lA + rs * 128);
    }
#pragma unroll
    for (int i = 0; i < 2; ++i) {                 // B: 64 rows
      const int rs = i * 32 + w * 8;
      gl_lds16((const char*)(Bt + (bnr + rs + g8) * 1024 + k0) + swz,
               (char*)lB + rs * 128);
    }
    __syncthreads();
#pragma unroll
    for (int kk = 0; kk < 64; kk += 32) {
      bf16x8 af[4], bfr[2];
#pragma unroll
      for (int fm = 0; fm < 4; ++fm) {
        int row = wm + fm * 16 + lr;
        af[fm] = *reinterpret_cast<const bf16x8*>(
            (const char*)lA + row * 128 + ((2 * kk + lg * 16) ^ ((lr & 7) << 4)));
      }
#pragma unroll
      for (int fn = 0; fn < 2; ++fn) {
        int row = wn + fn * 16 + lr;
        bfr[fn] = *reinterpret_cast<const bf16x8*>(
            (const char*)lB + row * 128 + ((2 * kk + lg * 16) ^ ((lr & 7) << 4)));
      }
#pragma unroll
      for (int fm = 0; fm < 4; ++fm)
#pragma unroll
        for (int fn = 0; fn < 2; ++fn)
          acc[fm][fn] = __builtin_amdgcn_mfma_f32_16x16x32_bf16(
              af[fm], bfr[fn], acc[fm][fn], 0, 0, 0);
    }
    __syncthreads();
  }

#pragma unroll
  for (int fm = 0; fm < 4; ++fm)
#pragma unroll
    for (int fn = 0; fn < 2; ++fn)
#pragma unroll
      for (int r = 0; r < 4; ++r) {
        int row = bm * 128 + wm + fm * 16 + lg * 4 + r;
        int col = bn * 64 + wn + fn * 16 + lr;
        outf[(size_t)row * 1024 + col] = acc[fm][fn][r] + bias[col];
      }
}

// ---------------------------------------------------------------- attention
// R13 verified: KVBLK=128. LDS: K [2][128x64], V^T [2][2][64x64], pl
// [4][16x128] XOR-swizzled. XCD-local grid, sum-15 pairing, base-2
// softmax + defer-max, cvt_pk pack.
__global__ __launch_bounds__(256, 2) void attn_kernel(
    const unsigned short* __restrict__ qb, const unsigned short* __restrict__ kb,
    const unsigned short* __restrict__ vt, unsigned short* __restrict__ attnb) {
  __shared__ __align__(16) unsigned short lK[2][128 * 64];
  __shared__ __align__(16) unsigned short lV[2][2][64 * 64];
  __shared__ __align__(16) unsigned short pl[4][16 * 128];
  const int bid = blockIdx.x;
  const int xcd = bid & 7, pos = bid >> 3;
  const int half = pos >> 5, idx = pos & 31;
  const int bh = xcd * 4 + half * 2 + (idx >> 4);
  const int qt = half ? (15 - (idx & 15)) : (idx & 15);
  const int q0 = qt * 128;
  const int w = threadIdx.x >> 6, lane = threadIdx.x & 63;
  const int lr = lane & 15, lg = lane >> 4;
  const int g8  = lane >> 3;
  const int swz = ((lane & 7) * 16) ^ (g8 << 4);

  const unsigned short* Kg = kb + (size_t)bh * 2048 * 64;
  const unsigned short* Vg = vt + (size_t)bh * 64 * 2048;

  auto stage = [&](int buf, int c) {
    const size_t kv0 = (size_t)c * 128;
#pragma unroll
    for (int i = 0; i < 4; ++i) {
      const int rs = i * 32 + w * 8;
      gl_lds16((const char*)(Kg + (kv0 + rs + g8) * 64) + swz,
               (char*)&lK[buf][0] + rs * 128);
    }
#pragma unroll
    for (int h = 0; h < 2; ++h)
#pragma unroll
      for (int i = 0; i < 2; ++i) {
        const int rs = i * 32 + w * 8;
        gl_lds16((const char*)(Vg + (size_t)(rs + g8) * 2048 + kv0 + h * 64) + swz,
                 (char*)&lV[buf][h][0] + rs * 128);
      }
  };

  bf16x8 qf[2][2];
#pragma unroll
  for (int qi = 0; qi < 2; ++qi)
#pragma unroll
    for (int kk = 0; kk < 2; ++kk)
      qf[qi][kk] = *reinterpret_cast<const bf16x8*>(
          &qb[((size_t)bh * 2048 + q0 + w * 32 + qi * 16 + lr) * 64 + kk * 32 + lg * 8]);

  f32x4 acc[2][4];
#pragma unroll
  for (int qi = 0; qi < 2; ++qi)
#pragma unroll
    for (int i = 0; i < 4; ++i) acc[qi][i] = f32x4{0.f, 0.f, 0.f, 0.f};
  float m[2] = {-1e30f, -1e30f}, rs[2] = {0.f, 0.f};

  const int nc = qt + 1;   // chunks of 128 keys
  stage(0, 0);

  for (int c = 0; c < nc; ++c) {
    const int cur = c & 1;
    __syncthreads();
    if (c + 1 < nc) stage(cur ^ 1, c + 1);

    // QK^T: S^T frags for 8 key-groups of 16
    f32x4 s[2][8];
#pragma unroll
    for (int qi = 0; qi < 2; ++qi)
#pragma unroll
      for (int i = 0; i < 8; ++i) s[qi][i] = f32x4{0.f, 0.f, 0.f, 0.f};
#pragma unroll
    for (int nf = 0; nf < 8; ++nf) {
      const int row = nf * 16 + lr;
      bf16x8 k0 = *reinterpret_cast<const bf16x8*>(
          (const char*)&lK[cur][0] + row * 128 + ((lg * 16) ^ ((lr & 7) << 4)));
      bf16x8 k1 = *reinterpret_cast<const bf16x8*>(
          (const char*)&lK[cur][0] + row * 128 + ((64 + lg * 16) ^ ((lr & 7) << 4)));
#pragma unroll
      for (int qi = 0; qi < 2; ++qi) {
        s[qi][nf] = __builtin_amdgcn_mfma_f32_16x16x32_bf16(k0, qf[qi][0], s[qi][nf], 0, 0, 0);
        s[qi][nf] = __builtin_amdgcn_mfma_f32_16x16x32_bf16(k1, qf[qi][1], s[qi][nf], 0, 0, 0);
      }
    }

#pragma unroll
    for (int qi = 0; qi < 2; ++qi) {
      const int qrow = q0 + w * 32 + qi * 16 + lr;
      const bool diag = (c * 128 + 127) > (q0 + w * 32 + qi * 16);
      float ps[8][4];
      float mx = -1e30f;
      if (diag) {
#pragma unroll
        for (int nf = 0; nf < 8; ++nf)
#pragma unroll
          for (int r = 0; r < 4; ++r) {
            int key = c * 128 + nf * 16 + lg * 4 + r;
            float sv = (key <= qrow) ? s[qi][nf][r] : -1e30f;
            ps[nf][r] = sv;
            mx = fmaxf(mx, sv);
          }
      } else {
#pragma unroll
        for (int nf = 0; nf < 8; ++nf)
#pragma unroll
          for (int r = 0; r < 4; ++r) {
            ps[nf][r] = s[qi][nf][r];
            mx = fmaxf(mx, ps[nf][r]);
          }
      }
      mx = fmaxf(mx, __shfl_xor(mx, 16));
      mx = fmaxf(mx, __shfl_xor(mx, 32));
      if (__any(mx > m[qi] + 8.f)) {            // defer-max (T13)
        float mn = fmaxf(m[qi], mx);
        float scl = exp2f(m[qi] - mn);
        m[qi] = mn;
        rs[qi] *= scl;
#pragma unroll
        for (int df = 0; df < 4; ++df) acc[qi][df] *= scl;
      }
      float ss = 0.f;
#pragma unroll
      for (int nf = 0; nf < 8; ++nf)
#pragma unroll
        for (int r = 0; r < 4; ++r) {
          float pe = exp2f(ps[nf][r] - m[qi]);
          ps[nf][r] = pe;
          ss += pe;
        }
      ss += __shfl_xor(ss, 16);
      ss += __shfl_xor(ss, 32);
      rs[qi] += ss;

      // pack P^T -> pl (swizzled, 8B writes), then PV for this qi
#pragma unroll
      for (int nf = 0; nf < 8; ++nf) {
        uint2 pk;
        pk.x = cvtpk(ps[nf][0], ps[nf][1]);
        pk.y = cvtpk(ps[nf][2], ps[nf][3]);
        *reinterpret_cast<uint2*>(
            (char*)&pl[w][0] + lr * 256 + ((nf * 32 + lg * 8) ^ ((lr & 7) << 4))) = pk;
      }
#pragma unroll
      for (int kk = 0; kk < 4; ++kk) {
        bf16x8 pf = *reinterpret_cast<const bf16x8*>(
            (const char*)&pl[w][0] + lr * 256 + ((kk * 64 + lg * 16) ^ ((lr & 7) << 4)));
#pragma unroll
        for (int df = 0; df < 4; ++df) {
          const int row = df * 16 + lr;
          bf16x8 vf = *reinterpret_cast<const bf16x8*>(
              (const char*)&lV[cur][kk >> 1][0] + row * 128 +
              (((kk & 1) * 64 + lg * 16) ^ ((lr & 7) << 4)));
          acc[qi][df] = __builtin_amdgcn_mfma_f32_16x16x32_bf16(vf, pf, acc[qi][df], 0, 0, 0);
        }
      }
    }
  }

  const int b = bh >> 4, h = bh & 15;
#pragma unroll
  for (int qi = 0; qi < 2; ++qi) {
    float inv = 1.f / rs[qi];
    int qrow = q0 + w * 32 + qi * 16 + lr;
#pragma unroll
    for (int df = 0; df < 4; ++df) {
      ushort4 ov;
      ov.x = f2b(acc[qi][df][0] * inv); ov.y = f2b(acc[qi][df][1] * inv);
      ov.z = f2b(acc[qi][df][2] * inv); ov.w = f2b(acc[qi][df][3] * inv);
      *reinterpret_cast<ushort4*>(
          &attnb[((size_t)b * 2048 + qrow) * 1024 + h * 64 + df * 16 + lg * 4]) = ov;
    }
  }
}

// ---------------------------------------------------------------- launch
extern "C" void kernel_launch(void* const* d_in, const int* in_sizes, int n_in,
                              void* d_out, int out_size, void* d_ws, size_t ws_size,
                              hipStream_t stream) {
  const float* x     = (const float*)d_in[0];
  const float* w_qkv = (const float*)d_in[1];
  const float* b_qkv = (const float*)d_in[2];
  const float* w_out = (const float*)d_in[3];
  const float* b_out = (const float*)d_in[4];
  float* out = (float*)d_out;
  char* ws = (char*)d_ws;

  unsigned short* xb    = (unsigned short*)(ws);               //  8.0 MB (-> vt)
  unsigned short* vt    = (unsigned short*)(ws);
  unsigned short* wqkvt = (unsigned short*)(ws + 8388608);     //  6.0 MB
  unsigned short* woutt = (unsigned short*)(ws + 14680064);    //  2.0 MB
  unsigned short* qb    = (unsigned short*)(ws + 16777216);    //  8.0 MB
  unsigned short* kb    = (unsigned short*)(ws + 25165824);    //  8.0 MB
  unsigned short* vb    = (unsigned short*)(ws + 33554432);    //  8.0 MB
  unsigned short* attnb = (unsigned short*)(ws + 41943040);    //  8.0 MB

  convert_bf16<<<2048, 256, 0, stream>>>(x, xb, 4194304 / 8);
  transpose_convert<<<1536, 256, 0, stream>>>(w_qkv, wqkvt, 1024, 3072);
  transpose_convert<<<512, 256, 0, stream>>>(w_out, woutt, 1024, 1024);
  gemm_qkv<<<dim3(24, 16), 512, 0, stream>>>(xb, wqkvt, b_qkv, qb, kb, vb);
  transpose_v<<<dim3(32, 32), 256, 0, stream>>>(vb, vt);
  attn_kernel<<<512, 256, 0, stream>>>(qb, kb, vt, attnb);
  gemm_out<<<dim3(16, 32), 256, 0, stream>>>(attnb, woutt, b_out, out);
}